// Round 5
// baseline (778.694 us; speedup 1.0000x reference)
//
#include <hip/hip_runtime.h>
#include <hip/hip_bf16.h>

// Problem constants (match reference)
#define NN 100000
#define NE 500000
#define DD 128
#define HID 128
#define RELS 4
#define NCLS 16
#define KTOT 640                     // BT row stride: 4*128 nbr + 128 root-sum
#define SCAN_B 1024
#define NCHUNK ((NN + SCAN_B - 1) / SCAN_B)   // 98

typedef __attribute__((ext_vector_type(8))) short s16x8;
typedef __attribute__((ext_vector_type(4))) float f32x4;

__device__ __forceinline__ float bf2f(unsigned short u) {
    return __uint_as_float(((unsigned int)u) << 16);
}
__device__ __forceinline__ unsigned short f2bfbits(float f) {
    __hip_bfloat16 h = __float2bfloat16(f);
    return *reinterpret_cast<unsigned short*>(&h);
}

// ---------------- CSR build ----------------

__global__ void hist_kernel(const int* __restrict__ e0, const int* __restrict__ e1,
                            const int* __restrict__ e2, const int* __restrict__ e3,
                            int* __restrict__ counts) {
    int i = blockIdx.x * 256 + threadIdx.x;
    int rel = blockIdx.y;
    if (i >= NE) return;
    const int* ep = (rel == 0) ? e0 : (rel == 1) ? e1 : (rel == 2) ? e2 : e3;
    int d = ep[NE + i];              // dst row
    atomicAdd(&counts[rel * NN + d], 1);
}

__global__ void scanA_kernel(const int* __restrict__ counts, int* __restrict__ bsums) {
    int rel = blockIdx.y, chunk = blockIdx.x;
    int i = chunk * SCAN_B + threadIdx.x;
    __shared__ int s[SCAN_B];
    int v = (i < NN) ? counts[rel * NN + i] : 0;
    s[threadIdx.x] = v;
    __syncthreads();
    for (int off = SCAN_B / 2; off > 0; off >>= 1) {
        if (threadIdx.x < off) s[threadIdx.x] += s[threadIdx.x + off];
        __syncthreads();
    }
    if (threadIdx.x == 0) bsums[rel * 128 + chunk] = s[0];
}

__global__ void scanB_kernel(int* __restrict__ bsums, int* __restrict__ rowptr) {
    int r = threadIdx.x;
    if (r < RELS) {
        int acc = 0;
        for (int c = 0; c < NCHUNK; ++c) {
            int v = bsums[r * 128 + c];
            bsums[r * 128 + c] = acc;
            acc += v;
        }
        rowptr[r * (NN + 1) + NN] = acc;   // == NE
    }
}

__global__ void scanC_kernel(const int* __restrict__ counts, const int* __restrict__ bsums,
                             int* __restrict__ rowptr) {
    int rel = blockIdx.y, chunk = blockIdx.x;
    int i = chunk * SCAN_B + threadIdx.x;
    __shared__ int s[SCAN_B];
    int v = (i < NN) ? counts[rel * NN + i] : 0;
    s[threadIdx.x] = v;
    __syncthreads();
    for (int off = 1; off < SCAN_B; off <<= 1) {
        int add = (threadIdx.x >= (unsigned)off) ? s[threadIdx.x - off] : 0;
        __syncthreads();
        s[threadIdx.x] += add;
        __syncthreads();
    }
    if (i < NN)
        rowptr[rel * (NN + 1) + i] = bsums[rel * 128 + chunk] + s[threadIdx.x] - v;
}

__global__ void fill_kernel(const int* __restrict__ e0, const int* __restrict__ e1,
                            const int* __restrict__ e2, const int* __restrict__ e3,
                            const int* __restrict__ rowptr, int* __restrict__ cursor,
                            int* __restrict__ col) {
    int i = blockIdx.x * 256 + threadIdx.x;
    int rel = blockIdx.y;
    if (i >= NE) return;
    const int* ep = (rel == 0) ? e0 : (rel == 1) ? e1 : (rel == 2) ? e2 : e3;
    int src = ep[i];
    int dst = ep[NE + i];
    int p = atomicAdd(&cursor[rel * NN + dst], 1);
    col[rel * NE + rowptr[rel * (NN + 1) + dst] + p] = src;
}

// ---------------- weight conversion ----------------
// BT[l][n][k] (bf16, k-major rows): k<512 -> W_nbr[l][k>>7][k&127][n]
//                                   k>=512 -> sum_r W_root[l][r][k-512][n]
// bsum[l][c] = sum_r b_nbr[l][r][c]  (fp32)

__global__ void wconv_kernel(const float* __restrict__ Wn, const float* __restrict__ Wr,
                             const float* __restrict__ bn, __hip_bfloat16* __restrict__ BT,
                             float* __restrict__ bsum) {
    int idx = blockIdx.x * 256 + threadIdx.x;
    if (idx < 2 * 128 * KTOT) {
        int l = (idx >= 128 * KTOT) ? 1 : 0;
        int rem = idx - l * 128 * KTOT;
        int n = rem & 127;
        int k = rem >> 7;            // 0..639
        float v;
        if (k < 512) {
            v = Wn[(((size_t)l * RELS + (k >> 7)) * 128 + (k & 127)) * 128 + n];
        } else {
            int kk = k - 512;
            v = 0.f;
            for (int r = 0; r < RELS; ++r)
                v += Wr[(((size_t)l * RELS + r) * 128 + kk) * 128 + n];
        }
        BT[((size_t)l * 128 + n) * KTOT + k] = __float2bfloat16(v);
    } else if (idx < 2 * 128 * KTOT + 256) {
        int i = idx - 2 * 128 * KTOT;
        int l = i >> 7, c = i & 127;
        float a = 0.f;
        for (int r = 0; r < RELS; ++r) a += bn[((size_t)l * RELS + r) * 128 + c];
        bsum[i] = a;
    }
}

// ---------------- x -> bf16 compact h0 [N,128] ----------------

__global__ void x2bf_kernel(const float* __restrict__ x, __hip_bfloat16* __restrict__ h) {
    int idx8 = blockIdx.x * 256 + threadIdx.x;    // one thread = 8 elements
    int node = idx8 >> 4;
    int c = (idx8 & 15) * 8;
    if (node >= NN) return;
    float4 f0 = *(const float4*)(x + (size_t)node * 128 + c);
    float4 f1 = *(const float4*)(x + (size_t)node * 128 + c + 4);
    uint4 o;
    o.x = f2bfbits(f0.x) | ((unsigned)f2bfbits(f0.y) << 16);
    o.y = f2bfbits(f0.z) | ((unsigned)f2bfbits(f0.w) << 16);
    o.z = f2bfbits(f1.x) | ((unsigned)f2bfbits(f1.y) << 16);
    o.w = f2bfbits(f1.z) | ((unsigned)f2bfbits(f1.w) << 16);
    *(uint4*)(h + (size_t)node * 128 + c) = o;
}

// ---------------- fused layer: gather-aggregate + MFMA GEMM ----------------
// hout = relu(0.25*([agg_0|agg_1|agg_2|agg_3|hin] @ BT^T + bsum)) as bf16 [N,128].
// Per 128-node block: 5 K-chunks of 128 (4 relations gathered into LDS, 1 self
// copied). No [N,512] cat intermediate. BM=128, BN=128, 4 waves (2x2), each
// wave 64x64 via 4x4 mfma_f32_16x16x32_bf16. XOR-swizzled LDS (T2).

__global__ __launch_bounds__(256) void fused_layer_kernel(
    const __hip_bfloat16* __restrict__ hin, __hip_bfloat16* __restrict__ hout,
    const __hip_bfloat16* __restrict__ BT, const float* __restrict__ bsum,
    const int* __restrict__ rowptr, const int* __restrict__ col, int M) {
    __shared__ uint4 smem4[4096];    // 64 KB: A tile 32 KB + B tile 32 KB
    char* AsB = (char*)smem4;        // [128 rows][128 k] bf16, swizzled 16B chunks
    char* BsB = (char*)smem4 + 32768;
    int t = threadIdx.x;
    int l = t & 63;
    int wave = t >> 6;
    int wm = wave >> 1, wn = wave & 1;
    int row0 = blockIdx.x * 128;

    int grp = t >> 4;                // gather: node group 0..15
    int lane = t & 15;               // gather: col chunk (16B)
    int brow = t >> 1;               // B/self staging: row 0..127
    int bhalf = t & 1;               // which 128B half

    int lrow = l & 15;               // MFMA fragment row/col within 16
    int lkg = l >> 4;                // MFMA k-group 0..3

    f32x4 acc[4][4];
#pragma unroll
    for (int i = 0; i < 4; ++i)
#pragma unroll
        for (int j = 0; j < 4; ++j) acc[i][j] = (f32x4){0.f, 0.f, 0.f, 0.f};

    for (int c = 0; c < 5; ++c) {
        // ---- load B tile chunk into regs (128B/thread) ----
        uint4 breg[8];
        {
            const __hip_bfloat16* gb = BT + (size_t)brow * KTOT + c * 128 + bhalf * 64;
#pragma unroll
            for (int j = 0; j < 8; ++j) breg[j] = *(const uint4*)(gb + j * 8);
        }
        __syncthreads();             // previous chunk's MFMA reads done
        // ---- write B tile to LDS (swizzled) ----
#pragma unroll
        for (int j = 0; j < 8; ++j) {
            int q = bhalf * 8 + j;
            *(uint4*)(BsB + brow * 256 + ((q ^ (brow & 7)) << 4)) = breg[j];
        }
        // ---- produce A tile ----
        if (c < 4) {
            // gather-aggregate relation c: 16 nodes in parallel, 8 rounds
            const int* __restrict__ rp = rowptr + c * (NN + 1);
            const int* __restrict__ cl = col + (size_t)c * NE;
#pragma unroll 1
            for (int nb = 0; nb < 8; ++nb) {
                int row = nb * 16 + grp;
                int node = row0 + row;
                float a[8] = {};
                float sc = 0.f;
                if (node < M) {
                    int s0 = rp[node], e0 = rp[node + 1];
                    int k = s0;
                    for (; k + 4 <= e0; k += 4) {
                        int i0 = cl[k], i1 = cl[k + 1], i2 = cl[k + 2], i3 = cl[k + 3];
                        uint4 v0 = *(const uint4*)(hin + (size_t)i0 * 128 + lane * 8);
                        uint4 v1 = *(const uint4*)(hin + (size_t)i1 * 128 + lane * 8);
                        uint4 v2 = *(const uint4*)(hin + (size_t)i2 * 128 + lane * 8);
                        uint4 v3 = *(const uint4*)(hin + (size_t)i3 * 128 + lane * 8);
                        a[0] += bf2f(v0.x & 0xffff) + bf2f(v1.x & 0xffff) + bf2f(v2.x & 0xffff) + bf2f(v3.x & 0xffff);
                        a[1] += bf2f(v0.x >> 16)    + bf2f(v1.x >> 16)    + bf2f(v2.x >> 16)    + bf2f(v3.x >> 16);
                        a[2] += bf2f(v0.y & 0xffff) + bf2f(v1.y & 0xffff) + bf2f(v2.y & 0xffff) + bf2f(v3.y & 0xffff);
                        a[3] += bf2f(v0.y >> 16)    + bf2f(v1.y >> 16)    + bf2f(v2.y >> 16)    + bf2f(v3.y >> 16);
                        a[4] += bf2f(v0.z & 0xffff) + bf2f(v1.z & 0xffff) + bf2f(v2.z & 0xffff) + bf2f(v3.z & 0xffff);
                        a[5] += bf2f(v0.z >> 16)    + bf2f(v1.z >> 16)    + bf2f(v2.z >> 16)    + bf2f(v3.z >> 16);
                        a[6] += bf2f(v0.w & 0xffff) + bf2f(v1.w & 0xffff) + bf2f(v2.w & 0xffff) + bf2f(v3.w & 0xffff);
                        a[7] += bf2f(v0.w >> 16)    + bf2f(v1.w >> 16)    + bf2f(v2.w >> 16)    + bf2f(v3.w >> 16);
                    }
                    for (; k < e0; ++k) {
                        int i0 = cl[k];
                        uint4 v0 = *(const uint4*)(hin + (size_t)i0 * 128 + lane * 8);
                        a[0] += bf2f(v0.x & 0xffff); a[1] += bf2f(v0.x >> 16);
                        a[2] += bf2f(v0.y & 0xffff); a[3] += bf2f(v0.y >> 16);
                        a[4] += bf2f(v0.z & 0xffff); a[5] += bf2f(v0.z >> 16);
                        a[6] += bf2f(v0.w & 0xffff); a[7] += bf2f(v0.w >> 16);
                    }
                    sc = (e0 > s0) ? 1.0f / (float)(e0 - s0) : 0.0f;
                }
                uint4 o;
                o.x = f2bfbits(a[0] * sc) | ((unsigned)f2bfbits(a[1] * sc) << 16);
                o.y = f2bfbits(a[2] * sc) | ((unsigned)f2bfbits(a[3] * sc) << 16);
                o.z = f2bfbits(a[4] * sc) | ((unsigned)f2bfbits(a[5] * sc) << 16);
                o.w = f2bfbits(a[6] * sc) | ((unsigned)f2bfbits(a[7] * sc) << 16);
                *(uint4*)(AsB + row * 256 + ((lane ^ (row & 7)) << 4)) = o;
            }
        } else {
            // self chunk: direct copy of hin rows
            int grow = row0 + brow;
            uint4 sreg[8];
            if (grow < M) {
                const __hip_bfloat16* gs = hin + (size_t)grow * 128 + bhalf * 64;
#pragma unroll
                for (int j = 0; j < 8; ++j) sreg[j] = *(const uint4*)(gs + j * 8);
            } else {
#pragma unroll
                for (int j = 0; j < 8; ++j) sreg[j] = make_uint4(0, 0, 0, 0);
            }
#pragma unroll
            for (int j = 0; j < 8; ++j) {
                int q = bhalf * 8 + j;
                *(uint4*)(AsB + brow * 256 + ((q ^ (brow & 7)) << 4)) = sreg[j];
            }
        }
        __syncthreads();
        // ---- MFMA over this K=128 chunk ----
#pragma unroll
        for (int kk = 0; kk < 4; ++kk) {
            s16x8 af[4], bfr[4];
            int q = kk * 4 + lkg;
#pragma unroll
            for (int mi = 0; mi < 4; ++mi) {
                int row = wm * 64 + mi * 16 + lrow;
                af[mi] = *(const s16x8*)(AsB + row * 256 + ((q ^ (row & 7)) << 4));
            }
#pragma unroll
            for (int ni = 0; ni < 4; ++ni) {
                int nrow = wn * 64 + ni * 16 + lrow;
                bfr[ni] = *(const s16x8*)(BsB + nrow * 256 + ((q ^ (nrow & 7)) << 4));
            }
#pragma unroll
            for (int mi = 0; mi < 4; ++mi)
#pragma unroll
                for (int ni = 0; ni < 4; ++ni)
                    acc[mi][ni] = __builtin_amdgcn_mfma_f32_16x16x32_bf16(
                        af[mi], bfr[ni], acc[mi][ni], 0, 0, 0);
        }
    }
    __syncthreads();   // LDS dead; reuse AsB region for C tile

    // ---- epilogue: bias + relu*0.25 -> bf16 C tile in LDS (swizzled) ----
    {
        int cr = l >> 4;
        int cc = l & 15;
#pragma unroll
        for (int ni = 0; ni < 4; ++ni) {
            int colg = wn * 64 + ni * 16 + cc;
            float bv2 = bsum[colg];
#pragma unroll
            for (int mi = 0; mi < 4; ++mi) {
#pragma unroll
                for (int r = 0; r < 4; ++r) {
                    int row = wm * 64 + mi * 16 + cr * 4 + r;
                    float v = fmaxf((acc[mi][ni][r] + bv2) * 0.25f, 0.f);
                    int byte = (row * 256 + colg * 2) ^ ((row & 7) << 4);
                    *(unsigned short*)(AsB + byte) = f2bfbits(v);
                }
            }
        }
    }
    __syncthreads();

    // ---- contiguous row writes: thread t owns row t>>1, half t&1 (128B) ----
    {
        int row = t >> 1;
        int half = t & 1;
        int grow = row0 + row;
        if (grow < M) {
            __hip_bfloat16* dst = hout + (size_t)grow * 128 + half * 64;
#pragma unroll
            for (int j = 0; j < 8; ++j) {
                int byte = (row * 256 + half * 128 + j * 16) ^ ((row & 7) << 4);
                *(uint4*)(dst + j * 8) = *(const uint4*)(AsB + byte);
            }
        }
    }
}

// ---------------- final linear: out[M,16] = h[M,128] @ W[128,16] + b ----------------

__global__ void final_linear_kernel(const __hip_bfloat16* __restrict__ h,
                                    const float* __restrict__ W,
                                    const float* __restrict__ bias, float* __restrict__ out) {
    __shared__ float Ws[128 * 16];
    __shared__ float Hs[16 * 132];
    int tid = threadIdx.x;
    int node0 = blockIdx.x * 16;
    for (int i = tid; i < 2048; i += 256) Ws[i] = W[i];
    {
        int g = tid >> 4, c = tid & 15;
        int node = node0 + g;
        float f[8] = {};
        if (node < NN) {
            uint4 v = *(const uint4*)(h + (size_t)node * 128 + c * 8);
            f[0] = bf2f(v.x & 0xffff); f[1] = bf2f(v.x >> 16);
            f[2] = bf2f(v.y & 0xffff); f[3] = bf2f(v.y >> 16);
            f[4] = bf2f(v.z & 0xffff); f[5] = bf2f(v.z >> 16);
            f[6] = bf2f(v.w & 0xffff); f[7] = bf2f(v.w >> 16);
        }
#pragma unroll
        for (int j = 0; j < 8; ++j) Hs[g * 132 + c * 8 + j] = f[j];
    }
    __syncthreads();
    int g = tid >> 4;
    int c = tid & 15;
    int node = node0 + g;
    if (node >= NN) return;
    float acc = bias[c];
#pragma unroll 8
    for (int k = 0; k < 128; ++k) acc += Hs[g * 132 + k] * Ws[k * 16 + c];
    out[node * NCLS + c] = acc;
}

// ---------------- launch ----------------

extern "C" void kernel_launch(void* const* d_in, const int* in_sizes, int n_in,
                              void* d_out, int out_size, void* d_ws, size_t ws_size,
                              hipStream_t stream) {
    const float* x     = (const float*)d_in[0];
    const int*   e0    = (const int*)d_in[1];
    const int*   e1    = (const int*)d_in[2];
    const int*   e2    = (const int*)d_in[3];
    const int*   e3    = (const int*)d_in[4];
    const float* W_nbr = (const float*)d_in[5];
    const float* b_nbr = (const float*)d_in[6];
    const float* W_root= (const float*)d_in[7];
    const float* lin_w = (const float*)d_in[8];
    const float* lin_b = (const float*)d_in[9];
    float* out = (float*)d_out;

    // workspace bump allocator (256B aligned)
    char* p = (char*)d_ws;
    auto alloc = [&](size_t bytes) -> void* {
        void* q = (void*)p;
        p += (bytes + 255) & ~(size_t)255;
        return q;
    };
    int*   counts = (int*)alloc((size_t)RELS * NN * 4);
    int*   rowptr = (int*)alloc((size_t)RELS * (NN + 1) * 4);
    int*   col    = (int*)alloc((size_t)RELS * NE * 4);
    int*   bsums  = (int*)alloc((size_t)RELS * 128 * 4);
    float* bsum   = (float*)alloc((size_t)2 * 128 * 4);
    __hip_bfloat16* BT = (__hip_bfloat16*)alloc((size_t)2 * 128 * KTOT * 2);
    __hip_bfloat16* h0 = (__hip_bfloat16*)alloc((size_t)NN * 128 * 2);
    __hip_bfloat16* h1 = (__hip_bfloat16*)alloc((size_t)NN * 128 * 2);
    __hip_bfloat16* h2 = (__hip_bfloat16*)alloc((size_t)NN * 128 * 2);

    const int eblocks = (NE + 255) / 256;

    // CSR build (shared by both layers)
    hipMemsetAsync(counts, 0, (size_t)RELS * NN * 4, stream);
    hist_kernel<<<dim3(eblocks, RELS), 256, 0, stream>>>(e0, e1, e2, e3, counts);
    scanA_kernel<<<dim3(NCHUNK, RELS), SCAN_B, 0, stream>>>(counts, bsums);
    scanB_kernel<<<1, 64, 0, stream>>>(bsums, rowptr);
    scanC_kernel<<<dim3(NCHUNK, RELS), SCAN_B, 0, stream>>>(counts, bsums, rowptr);
    hipMemsetAsync(counts, 0, (size_t)RELS * NN * 4, stream);
    fill_kernel<<<dim3(eblocks, RELS), 256, 0, stream>>>(e0, e1, e2, e3, rowptr, counts, col);

    // weights -> bf16 transposed (+ root-sum fold + bias sum)
    wconv_kernel<<<(2 * 128 * KTOT + 256 + 255) / 256, 256, 0, stream>>>(
        W_nbr, W_root, b_nbr, BT, bsum);

    // x -> bf16 compact h0
    x2bf_kernel<<<(NN * 128 / 8 + 255) / 256, 256, 0, stream>>>(x, h0);

    const int gemm_blocks = (NN + 127) / 128;

    // layer 1: h0 -> h1   (fused gather + GEMM, no cat intermediate)
    fused_layer_kernel<<<gemm_blocks, 256, 0, stream>>>(h0, h1, BT, bsum, rowptr, col, NN);
    // layer 2: h1 -> h2
    fused_layer_kernel<<<gemm_blocks, 256, 0, stream>>>(h1, h2, BT + (size_t)128 * KTOT,
                                                        bsum + 128, rowptr, col, NN);

    final_linear_kernel<<<(NN + 15) / 16, 256, 0, stream>>>(h2, lin_w, lin_b, out);
}

// Round 6
// 648.826 us; speedup vs baseline: 1.2002x; 1.2002x over previous
//
#include <hip/hip_runtime.h>
#include <hip/hip_bf16.h>

// Problem constants (match reference)
#define NN 100000
#define NE 500000
#define DD 128
#define HID 128
#define RELS 4
#define NCLS 16
#define KTOT 640                     // BT row stride: 4*128 nbr + 128 root-sum
#define SCAN_B 1024
#define NCHUNK ((NN + SCAN_B - 1) / SCAN_B)   // 98

typedef __attribute__((ext_vector_type(8))) short s16x8;
typedef __attribute__((ext_vector_type(4))) float f32x4;

__device__ __forceinline__ float bf2f(unsigned short u) {
    return __uint_as_float(((unsigned int)u) << 16);
}
__device__ __forceinline__ unsigned short f2bfbits(float f) {
    __hip_bfloat16 h = __float2bfloat16(f);
    return *reinterpret_cast<unsigned short*>(&h);
}

// ---------------- CSR build ----------------

__global__ void hist_kernel(const int* __restrict__ e0, const int* __restrict__ e1,
                            const int* __restrict__ e2, const int* __restrict__ e3,
                            int* __restrict__ counts) {
    int i = blockIdx.x * 256 + threadIdx.x;
    int rel = blockIdx.y;
    if (i >= NE) return;
    const int* ep = (rel == 0) ? e0 : (rel == 1) ? e1 : (rel == 2) ? e2 : e3;
    int d = ep[NE + i];              // dst row
    atomicAdd(&counts[rel * NN + d], 1);
}

__global__ void scanA_kernel(const int* __restrict__ counts, int* __restrict__ bsums) {
    int rel = blockIdx.y, chunk = blockIdx.x;
    int i = chunk * SCAN_B + threadIdx.x;
    __shared__ int s[SCAN_B];
    int v = (i < NN) ? counts[rel * NN + i] : 0;
    s[threadIdx.x] = v;
    __syncthreads();
    for (int off = SCAN_B / 2; off > 0; off >>= 1) {
        if (threadIdx.x < off) s[threadIdx.x] += s[threadIdx.x + off];
        __syncthreads();
    }
    if (threadIdx.x == 0) bsums[rel * 128 + chunk] = s[0];
}

__global__ void scanB_kernel(int* __restrict__ bsums, int* __restrict__ rowptr) {
    int r = threadIdx.x;
    if (r < RELS) {
        int acc = 0;
        for (int c = 0; c < NCHUNK; ++c) {
            int v = bsums[r * 128 + c];
            bsums[r * 128 + c] = acc;
            acc += v;
        }
        rowptr[r * (NN + 1) + NN] = acc;   // == NE
    }
}

__global__ void scanC_kernel(const int* __restrict__ counts, const int* __restrict__ bsums,
                             int* __restrict__ rowptr) {
    int rel = blockIdx.y, chunk = blockIdx.x;
    int i = chunk * SCAN_B + threadIdx.x;
    __shared__ int s[SCAN_B];
    int v = (i < NN) ? counts[rel * NN + i] : 0;
    s[threadIdx.x] = v;
    __syncthreads();
    for (int off = 1; off < SCAN_B; off <<= 1) {
        int add = (threadIdx.x >= (unsigned)off) ? s[threadIdx.x - off] : 0;
        __syncthreads();
        s[threadIdx.x] += add;
        __syncthreads();
    }
    if (i < NN)
        rowptr[rel * (NN + 1) + i] = bsums[rel * 128 + chunk] + s[threadIdx.x] - v;
}

__global__ void fill_kernel(const int* __restrict__ e0, const int* __restrict__ e1,
                            const int* __restrict__ e2, const int* __restrict__ e3,
                            const int* __restrict__ rowptr, int* __restrict__ cursor,
                            int* __restrict__ col) {
    int i = blockIdx.x * 256 + threadIdx.x;
    int rel = blockIdx.y;
    if (i >= NE) return;
    const int* ep = (rel == 0) ? e0 : (rel == 1) ? e1 : (rel == 2) ? e2 : e3;
    int src = ep[i];
    int dst = ep[NE + i];
    int p = atomicAdd(&cursor[rel * NN + dst], 1);
    col[rel * NE + rowptr[rel * (NN + 1) + dst] + p] = src;
}

// ---------------- weight conversion ----------------
// BT[l][n][k] (bf16, k-major rows): k<512 -> W_nbr[l][k>>7][k&127][n]
//                                   k>=512 -> sum_r W_root[l][r][k-512][n]
// bsum[l][c] = sum_r b_nbr[l][r][c]  (fp32)

__global__ void wconv_kernel(const float* __restrict__ Wn, const float* __restrict__ Wr,
                             const float* __restrict__ bn, __hip_bfloat16* __restrict__ BT,
                             float* __restrict__ bsum) {
    int idx = blockIdx.x * 256 + threadIdx.x;
    if (idx < 2 * 128 * KTOT) {
        int l = (idx >= 128 * KTOT) ? 1 : 0;
        int rem = idx - l * 128 * KTOT;
        int n = rem & 127;
        int k = rem >> 7;            // 0..639
        float v;
        if (k < 512) {
            v = Wn[(((size_t)l * RELS + (k >> 7)) * 128 + (k & 127)) * 128 + n];
        } else {
            int kk = k - 512;
            v = 0.f;
            for (int r = 0; r < RELS; ++r)
                v += Wr[(((size_t)l * RELS + r) * 128 + kk) * 128 + n];
        }
        BT[((size_t)l * 128 + n) * KTOT + k] = __float2bfloat16(v);
    } else if (idx < 2 * 128 * KTOT + 256) {
        int i = idx - 2 * 128 * KTOT;
        int l = i >> 7, c = i & 127;
        float a = 0.f;
        for (int r = 0; r < RELS; ++r) a += bn[((size_t)l * RELS + r) * 128 + c];
        bsum[i] = a;
    }
}

// ---------------- x -> bf16 compact h0 [N,128] ----------------

__global__ void x2bf_kernel(const float* __restrict__ x, __hip_bfloat16* __restrict__ h) {
    int idx8 = blockIdx.x * 256 + threadIdx.x;    // one thread = 8 elements
    int node = idx8 >> 4;
    int c = (idx8 & 15) * 8;
    if (node >= NN) return;
    float4 f0 = *(const float4*)(x + (size_t)node * 128 + c);
    float4 f1 = *(const float4*)(x + (size_t)node * 128 + c + 4);
    uint4 o;
    o.x = f2bfbits(f0.x) | ((unsigned)f2bfbits(f0.y) << 16);
    o.y = f2bfbits(f0.z) | ((unsigned)f2bfbits(f0.w) << 16);
    o.z = f2bfbits(f1.x) | ((unsigned)f2bfbits(f1.y) << 16);
    o.w = f2bfbits(f1.z) | ((unsigned)f2bfbits(f1.w) << 16);
    *(uint4*)(h + (size_t)node * 128 + c) = o;
}

// ---------------- fused layer: gather-aggregate + MFMA GEMM (BM=64) ----------------
// hout = relu(0.25*([agg_0|..|agg_3|hin] @ BT^T + bsum)) as bf16 [N,128].
// 10 K-chunks of 64 (rel = c>>1, half = c&1; c>=8 -> self). Per chunk the
// gather loads each edge's 128B half-row (= 1 cache line). 256 threads =
// 4 waves (2x2), wave tile 32x64 via 2x4 mfma_f32_16x16x32_bf16.
// LDS 24 KB (A 8K + B 16K) -> ~5-6 blocks/CU, ~20 waves/CU for gather latency.

__global__ __launch_bounds__(256, 5) void fused_layer_kernel(
    const __hip_bfloat16* __restrict__ hin, __hip_bfloat16* __restrict__ hout,
    const __hip_bfloat16* __restrict__ BT, const float* __restrict__ bsum,
    const int* __restrict__ rowptr, const int* __restrict__ col, int M) {
    __shared__ uint4 smem4[1536];    // 24 KB
    char* AsB = (char*)smem4;        // [64 rows][64 k] bf16, swizzled 16B chunks
    char* BsB = (char*)smem4 + 8192; // [128 n ][64 k]
    int t = threadIdx.x;
    int l = t & 63;
    int wave = t >> 6;
    int wm = wave >> 1, wn = wave & 1;
    int row0 = blockIdx.x * 64;

    int grp = t >> 3;                // gather: node group 0..31
    int lane = t & 7;                // gather: 16B chunk within 128B half-row
    int bn_ = t >> 1;                // B stage: n row 0..127
    int bj = t & 1;                  // B stage: which 32-elem half

    int lrow = l & 15;               // MFMA fragment row/col within 16
    int lkg = l >> 4;                // MFMA k-group 0..3

    f32x4 acc[2][4];
#pragma unroll
    for (int i = 0; i < 2; ++i)
#pragma unroll
        for (int j = 0; j < 4; ++j) acc[i][j] = (f32x4){0.f, 0.f, 0.f, 0.f};

    for (int c = 0; c < 10; ++c) {
        // ---- B chunk -> regs (64B/thread) ----
        uint4 breg[4];
        {
            const __hip_bfloat16* gb = BT + (size_t)bn_ * KTOT + c * 64 + bj * 32;
#pragma unroll
            for (int j = 0; j < 4; ++j) breg[j] = *(const uint4*)(gb + j * 8);
        }
        if (c) __syncthreads();      // previous chunk's LDS reads done
#pragma unroll
        for (int j = 0; j < 4; ++j) {
            int q = bj * 4 + j;
            *(uint4*)(BsB + bn_ * 128 + ((q ^ (bn_ & 7)) << 4)) = breg[j];
        }
        // ---- A chunk ----
        if (c < 8) {
            int rel = c >> 1, half = c & 1;
            const int* __restrict__ rp = rowptr + rel * (NN + 1);
            const int* __restrict__ cl = col + (size_t)rel * NE;
            const __hip_bfloat16* __restrict__ hsrc = hin + half * 64 + lane * 8;
#pragma unroll
            for (int nb = 0; nb < 2; ++nb) {
                int row = nb * 32 + grp;
                int node = row0 + row;
                float a[8] = {};
                float sc = 0.f;
                if (node < M) {
                    int s0 = rp[node], e0 = rp[node + 1];
                    int k = s0;
                    for (; k + 4 <= e0; k += 4) {
                        int i0 = cl[k], i1 = cl[k + 1], i2 = cl[k + 2], i3 = cl[k + 3];
                        uint4 v0 = *(const uint4*)(hsrc + (size_t)i0 * 128);
                        uint4 v1 = *(const uint4*)(hsrc + (size_t)i1 * 128);
                        uint4 v2 = *(const uint4*)(hsrc + (size_t)i2 * 128);
                        uint4 v3 = *(const uint4*)(hsrc + (size_t)i3 * 128);
                        a[0] += bf2f(v0.x & 0xffff) + bf2f(v1.x & 0xffff) + bf2f(v2.x & 0xffff) + bf2f(v3.x & 0xffff);
                        a[1] += bf2f(v0.x >> 16)    + bf2f(v1.x >> 16)    + bf2f(v2.x >> 16)    + bf2f(v3.x >> 16);
                        a[2] += bf2f(v0.y & 0xffff) + bf2f(v1.y & 0xffff) + bf2f(v2.y & 0xffff) + bf2f(v3.y & 0xffff);
                        a[3] += bf2f(v0.y >> 16)    + bf2f(v1.y >> 16)    + bf2f(v2.y >> 16)    + bf2f(v3.y >> 16);
                        a[4] += bf2f(v0.z & 0xffff) + bf2f(v1.z & 0xffff) + bf2f(v2.z & 0xffff) + bf2f(v3.z & 0xffff);
                        a[5] += bf2f(v0.z >> 16)    + bf2f(v1.z >> 16)    + bf2f(v2.z >> 16)    + bf2f(v3.z >> 16);
                        a[6] += bf2f(v0.w & 0xffff) + bf2f(v1.w & 0xffff) + bf2f(v2.w & 0xffff) + bf2f(v3.w & 0xffff);
                        a[7] += bf2f(v0.w >> 16)    + bf2f(v1.w >> 16)    + bf2f(v2.w >> 16)    + bf2f(v3.w >> 16);
                    }
                    for (; k < e0; ++k) {
                        int i0 = cl[k];
                        uint4 v0 = *(const uint4*)(hsrc + (size_t)i0 * 128);
                        a[0] += bf2f(v0.x & 0xffff); a[1] += bf2f(v0.x >> 16);
                        a[2] += bf2f(v0.y & 0xffff); a[3] += bf2f(v0.y >> 16);
                        a[4] += bf2f(v0.z & 0xffff); a[5] += bf2f(v0.z >> 16);
                        a[6] += bf2f(v0.w & 0xffff); a[7] += bf2f(v0.w >> 16);
                    }
                    sc = (e0 > s0) ? 1.0f / (float)(e0 - s0) : 0.0f;
                }
                uint4 o;
                o.x = f2bfbits(a[0] * sc) | ((unsigned)f2bfbits(a[1] * sc) << 16);
                o.y = f2bfbits(a[2] * sc) | ((unsigned)f2bfbits(a[3] * sc) << 16);
                o.z = f2bfbits(a[4] * sc) | ((unsigned)f2bfbits(a[5] * sc) << 16);
                o.w = f2bfbits(a[6] * sc) | ((unsigned)f2bfbits(a[7] * sc) << 16);
                *(uint4*)(AsB + row * 128 + ((lane ^ (row & 7)) << 4)) = o;
            }
        } else {
            // self chunk: copy hin rows (32B/thread)
            int half = c & 1;
            int row = t >> 2, part = t & 3;
            int node = row0 + row;
            uint4 v0 = make_uint4(0, 0, 0, 0), v1 = make_uint4(0, 0, 0, 0);
            if (node < M) {
                const __hip_bfloat16* gs = hin + (size_t)node * 128 + half * 64 + part * 16;
                v0 = *(const uint4*)gs;
                v1 = *(const uint4*)(gs + 8);
            }
            int q0 = part * 2, q1 = part * 2 + 1;
            *(uint4*)(AsB + row * 128 + ((q0 ^ (row & 7)) << 4)) = v0;
            *(uint4*)(AsB + row * 128 + ((q1 ^ (row & 7)) << 4)) = v1;
        }
        __syncthreads();
        // ---- MFMA over this K=64 chunk ----
#pragma unroll
        for (int kk = 0; kk < 2; ++kk) {
            s16x8 af[2], bfr[4];
            int q = kk * 4 + lkg;
#pragma unroll
            for (int mi = 0; mi < 2; ++mi) {
                int row = wm * 32 + mi * 16 + lrow;
                af[mi] = *(const s16x8*)(AsB + row * 128 + ((q ^ (row & 7)) << 4));
            }
#pragma unroll
            for (int ni = 0; ni < 4; ++ni) {
                int nrow = wn * 64 + ni * 16 + lrow;
                bfr[ni] = *(const s16x8*)(BsB + nrow * 128 + ((q ^ (nrow & 7)) << 4));
            }
#pragma unroll
            for (int mi = 0; mi < 2; ++mi)
#pragma unroll
                for (int ni = 0; ni < 4; ++ni)
                    acc[mi][ni] = __builtin_amdgcn_mfma_f32_16x16x32_bf16(
                        af[mi], bfr[ni], acc[mi][ni], 0, 0, 0);
        }
    }
    __syncthreads();   // LDS dead; reuse for C tile [64][128] bf16 (16 KB)

    // ---- epilogue: bias + relu*0.25 -> bf16 C tile in LDS (swizzled) ----
    {
        int cr = l >> 4;
        int cc = l & 15;
#pragma unroll
        for (int ni = 0; ni < 4; ++ni) {
            int colg = wn * 64 + ni * 16 + cc;
            float bv2 = bsum[colg];
            int q = colg >> 3;
            int cb = (colg & 7) * 2;
#pragma unroll
            for (int mi = 0; mi < 2; ++mi) {
#pragma unroll
                for (int r = 0; r < 4; ++r) {
                    int row = wm * 32 + mi * 16 + cr * 4 + r;
                    float v = fmaxf((acc[mi][ni][r] + bv2) * 0.25f, 0.f);
                    int byte = row * 256 + ((q ^ (row & 15)) << 4) + cb;
                    *(unsigned short*)((char*)smem4 + byte) = f2bfbits(v);
                }
            }
        }
    }
    __syncthreads();

    // ---- contiguous row writes: thread t owns row t>>2, quarter t&3 (64B) ----
    {
        int row = t >> 2;
        int part = t & 3;
        int grow = row0 + row;
        if (grow < M) {
            __hip_bfloat16* dst = hout + (size_t)grow * 128 + part * 32;
#pragma unroll
            for (int j = 0; j < 4; ++j) {
                int q = part * 4 + j;
                uint4 v = *(const uint4*)((char*)smem4 + row * 256 + ((q ^ (row & 15)) << 4));
                *(uint4*)(dst + j * 8) = v;
            }
        }
    }
}

// ---------------- final linear: out[M,16] = h[M,128] @ W[128,16] + b ----------------

__global__ void final_linear_kernel(const __hip_bfloat16* __restrict__ h,
                                    const float* __restrict__ W,
                                    const float* __restrict__ bias, float* __restrict__ out) {
    __shared__ float Ws[128 * 16];
    __shared__ float Hs[16 * 132];
    int tid = threadIdx.x;
    int node0 = blockIdx.x * 16;
    for (int i = tid; i < 2048; i += 256) Ws[i] = W[i];
    {
        int g = tid >> 4, c = tid & 15;
        int node = node0 + g;
        float f[8] = {};
        if (node < NN) {
            uint4 v = *(const uint4*)(h + (size_t)node * 128 + c * 8);
            f[0] = bf2f(v.x & 0xffff); f[1] = bf2f(v.x >> 16);
            f[2] = bf2f(v.y & 0xffff); f[3] = bf2f(v.y >> 16);
            f[4] = bf2f(v.z & 0xffff); f[5] = bf2f(v.z >> 16);
            f[6] = bf2f(v.w & 0xffff); f[7] = bf2f(v.w >> 16);
        }
#pragma unroll
        for (int j = 0; j < 8; ++j) Hs[g * 132 + c * 8 + j] = f[j];
    }
    __syncthreads();
    int g = tid >> 4;
    int c = tid & 15;
    int node = node0 + g;
    if (node >= NN) return;
    float acc = bias[c];
#pragma unroll 8
    for (int k = 0; k < 128; ++k) acc += Hs[g * 132 + k] * Ws[k * 16 + c];
    out[node * NCLS + c] = acc;
}

// ---------------- launch ----------------

extern "C" void kernel_launch(void* const* d_in, const int* in_sizes, int n_in,
                              void* d_out, int out_size, void* d_ws, size_t ws_size,
                              hipStream_t stream) {
    const float* x     = (const float*)d_in[0];
    const int*   e0    = (const int*)d_in[1];
    const int*   e1    = (const int*)d_in[2];
    const int*   e2    = (const int*)d_in[3];
    const int*   e3    = (const int*)d_in[4];
    const float* W_nbr = (const float*)d_in[5];
    const float* b_nbr = (const float*)d_in[6];
    const float* W_root= (const float*)d_in[7];
    const float* lin_w = (const float*)d_in[8];
    const float* lin_b = (const float*)d_in[9];
    float* out = (float*)d_out;

    // workspace bump allocator (256B aligned)
    char* p = (char*)d_ws;
    auto alloc = [&](size_t bytes) -> void* {
        void* q = (void*)p;
        p += (bytes + 255) & ~(size_t)255;
        return q;
    };
    int*   counts = (int*)alloc((size_t)RELS * NN * 4);
    int*   rowptr = (int*)alloc((size_t)RELS * (NN + 1) * 4);
    int*   col    = (int*)alloc((size_t)RELS * NE * 4);
    int*   bsums  = (int*)alloc((size_t)RELS * 128 * 4);
    float* bsum   = (float*)alloc((size_t)2 * 128 * 4);
    __hip_bfloat16* BT = (__hip_bfloat16*)alloc((size_t)2 * 128 * KTOT * 2);
    __hip_bfloat16* h0 = (__hip_bfloat16*)alloc((size_t)NN * 128 * 2);
    __hip_bfloat16* h1 = (__hip_bfloat16*)alloc((size_t)NN * 128 * 2);
    __hip_bfloat16* h2 = (__hip_bfloat16*)alloc((size_t)NN * 128 * 2);

    const int eblocks = (NE + 255) / 256;

    // CSR build (shared by both layers)
    hipMemsetAsync(counts, 0, (size_t)RELS * NN * 4, stream);
    hist_kernel<<<dim3(eblocks, RELS), 256, 0, stream>>>(e0, e1, e2, e3, counts);
    scanA_kernel<<<dim3(NCHUNK, RELS), SCAN_B, 0, stream>>>(counts, bsums);
    scanB_kernel<<<1, 64, 0, stream>>>(bsums, rowptr);
    scanC_kernel<<<dim3(NCHUNK, RELS), SCAN_B, 0, stream>>>(counts, bsums, rowptr);
    hipMemsetAsync(counts, 0, (size_t)RELS * NN * 4, stream);
    fill_kernel<<<dim3(eblocks, RELS), 256, 0, stream>>>(e0, e1, e2, e3, rowptr, counts, col);

    // weights -> bf16 transposed (+ root-sum fold + bias sum)
    wconv_kernel<<<(2 * 128 * KTOT + 256 + 255) / 256, 256, 0, stream>>>(
        W_nbr, W_root, b_nbr, BT, bsum);

    // x -> bf16 compact h0
    x2bf_kernel<<<(NN * 128 / 8 + 255) / 256, 256, 0, stream>>>(x, h0);

    const int fblocks = (NN + 63) / 64;

    // layer 1: h0 -> h1   (fused gather + GEMM, no cat intermediate)
    fused_layer_kernel<<<fblocks, 256, 0, stream>>>(h0, h1, BT, bsum, rowptr, col, NN);
    // layer 2: h1 -> h2
    fused_layer_kernel<<<fblocks, 256, 0, stream>>>(h1, h2, BT + (size_t)128 * KTOT,
                                                    bsum + 128, rowptr, col, NN);

    final_linear_kernel<<<(NN + 15) / 16, 256, 0, stream>>>(h2, lin_w, lin_b, out);
}

// Round 7
// 597.075 us; speedup vs baseline: 1.3042x; 1.0867x over previous
//
#include <hip/hip_runtime.h>
#include <hip/hip_bf16.h>

// Problem constants (match reference)
#define NN 100000
#define NE 500000
#define DD 128
#define HID 128
#define RELS 4
#define NCLS 16
#define KTOT 640                     // BT row stride: 4*128 nbr + 128 root-sum
#define SCAN_B 1024
#define NCHUNK ((NN + SCAN_B - 1) / SCAN_B)   // 98

typedef __attribute__((ext_vector_type(8))) short s16x8;
typedef __attribute__((ext_vector_type(4))) float f32x4;

__device__ __forceinline__ float bf2f(unsigned short u) {
    return __uint_as_float(((unsigned int)u) << 16);
}
__device__ __forceinline__ unsigned short f2bfbits(float f) {
    __hip_bfloat16 h = __float2bfloat16(f);
    return *reinterpret_cast<unsigned short*>(&h);
}

// ---------------- CSR build ----------------

__global__ void hist_kernel(const int* __restrict__ e0, const int* __restrict__ e1,
                            const int* __restrict__ e2, const int* __restrict__ e3,
                            int* __restrict__ counts) {
    int i = blockIdx.x * 256 + threadIdx.x;
    int rel = blockIdx.y;
    if (i >= NE) return;
    const int* ep = (rel == 0) ? e0 : (rel == 1) ? e1 : (rel == 2) ? e2 : e3;
    int d = ep[NE + i];              // dst row
    atomicAdd(&counts[rel * NN + d], 1);
}

__global__ void scanA_kernel(const int* __restrict__ counts, int* __restrict__ bsums) {
    int rel = blockIdx.y, chunk = blockIdx.x;
    int i = chunk * SCAN_B + threadIdx.x;
    __shared__ int s[SCAN_B];
    int v = (i < NN) ? counts[rel * NN + i] : 0;
    s[threadIdx.x] = v;
    __syncthreads();
    for (int off = SCAN_B / 2; off > 0; off >>= 1) {
        if (threadIdx.x < off) s[threadIdx.x] += s[threadIdx.x + off];
        __syncthreads();
    }
    if (threadIdx.x == 0) bsums[rel * 128 + chunk] = s[0];
}

__global__ void scanB_kernel(int* __restrict__ bsums, int* __restrict__ rowptr) {
    int r = threadIdx.x;
    if (r < RELS) {
        int acc = 0;
        for (int c = 0; c < NCHUNK; ++c) {
            int v = bsums[r * 128 + c];
            bsums[r * 128 + c] = acc;
            acc += v;
        }
        rowptr[r * (NN + 1) + NN] = acc;   // == NE
    }
}

__global__ void scanC_kernel(const int* __restrict__ counts, const int* __restrict__ bsums,
                             int* __restrict__ rowptr) {
    int rel = blockIdx.y, chunk = blockIdx.x;
    int i = chunk * SCAN_B + threadIdx.x;
    __shared__ int s[SCAN_B];
    int v = (i < NN) ? counts[rel * NN + i] : 0;
    s[threadIdx.x] = v;
    __syncthreads();
    for (int off = 1; off < SCAN_B; off <<= 1) {
        int add = (threadIdx.x >= (unsigned)off) ? s[threadIdx.x - off] : 0;
        __syncthreads();
        s[threadIdx.x] += add;
        __syncthreads();
    }
    if (i < NN)
        rowptr[rel * (NN + 1) + i] = bsums[rel * 128 + chunk] + s[threadIdx.x] - v;
}

__global__ void fill_kernel(const int* __restrict__ e0, const int* __restrict__ e1,
                            const int* __restrict__ e2, const int* __restrict__ e3,
                            const int* __restrict__ rowptr, int* __restrict__ cursor,
                            int* __restrict__ col) {
    int i = blockIdx.x * 256 + threadIdx.x;
    int rel = blockIdx.y;
    if (i >= NE) return;
    const int* ep = (rel == 0) ? e0 : (rel == 1) ? e1 : (rel == 2) ? e2 : e3;
    int src = ep[i];
    int dst = ep[NE + i];
    int p = atomicAdd(&cursor[rel * NN + dst], 1);
    col[rel * NE + rowptr[rel * (NN + 1) + dst] + p] = src;
}

// ---------------- weight conversion ----------------
// BT[l][n][k] (bf16, k-major rows): k<512 -> W_nbr[l][k>>7][k&127][n]
//                                   k>=512 -> sum_r W_root[l][r][k-512][n]
// bsum[l][c] = sum_r b_nbr[l][r][c]  (fp32)

__global__ void wconv_kernel(const float* __restrict__ Wn, const float* __restrict__ Wr,
                             const float* __restrict__ bn, __hip_bfloat16* __restrict__ BT,
                             float* __restrict__ bsum) {
    int idx = blockIdx.x * 256 + threadIdx.x;
    if (idx < 2 * 128 * KTOT) {
        int l = (idx >= 128 * KTOT) ? 1 : 0;
        int rem = idx - l * 128 * KTOT;
        int n = rem & 127;
        int k = rem >> 7;            // 0..639
        float v;
        if (k < 512) {
            v = Wn[(((size_t)l * RELS + (k >> 7)) * 128 + (k & 127)) * 128 + n];
        } else {
            int kk = k - 512;
            v = 0.f;
            for (int r = 0; r < RELS; ++r)
                v += Wr[(((size_t)l * RELS + r) * 128 + kk) * 128 + n];
        }
        BT[((size_t)l * 128 + n) * KTOT + k] = __float2bfloat16(v);
    } else if (idx < 2 * 128 * KTOT + 256) {
        int i = idx - 2 * 128 * KTOT;
        int l = i >> 7, c = i & 127;
        float a = 0.f;
        for (int r = 0; r < RELS; ++r) a += bn[((size_t)l * RELS + r) * 128 + c];
        bsum[i] = a;
    }
}

// ---------------- x -> bf16 compact h0 [N,128] ----------------

__global__ void x2bf_kernel(const float* __restrict__ x, __hip_bfloat16* __restrict__ h) {
    int idx8 = blockIdx.x * 256 + threadIdx.x;    // one thread = 8 elements
    int node = idx8 >> 4;
    int c = (idx8 & 15) * 8;
    if (node >= NN) return;
    float4 f0 = *(const float4*)(x + (size_t)node * 128 + c);
    float4 f1 = *(const float4*)(x + (size_t)node * 128 + c + 4);
    uint4 o;
    o.x = f2bfbits(f0.x) | ((unsigned)f2bfbits(f0.y) << 16);
    o.y = f2bfbits(f0.z) | ((unsigned)f2bfbits(f0.w) << 16);
    o.z = f2bfbits(f1.x) | ((unsigned)f2bfbits(f1.y) << 16);
    o.w = f2bfbits(f1.z) | ((unsigned)f2bfbits(f1.w) << 16);
    *(uint4*)(h + (size_t)node * 128 + c) = o;
}

// ---------------- mean aggregation: compact bf16 -> compact agg[rel][N,128] ----------------
// 16 lanes per node (16B each), 16 nodes per 256-thread block, grid.y = relation.
// No LDS, low VGPR -> max occupancy; gather latency hidden by TLP + unroll-4 ILP.

__global__ void aggregate_kernel(const int* __restrict__ rowptr, const int* __restrict__ col,
                                 const __hip_bfloat16* __restrict__ hin,
                                 __hip_bfloat16* __restrict__ agg) {
    int rel = blockIdx.y;
    int t = threadIdx.x;
    int node = blockIdx.x * 16 + (t >> 4);
    int lane = t & 15;
    const int* __restrict__ rp = rowptr + rel * (NN + 1);
    const int* __restrict__ cl = col + (size_t)rel * NE;
    const __hip_bfloat16* __restrict__ hsrc = hin + lane * 8;
    int s = rp[node], e = rp[node + 1];
    float a[8] = {};
    int k = s;
    for (; k + 4 <= e; k += 4) {
        int i0 = cl[k], i1 = cl[k + 1], i2 = cl[k + 2], i3 = cl[k + 3];
        uint4 v0 = *(const uint4*)(hsrc + (size_t)i0 * 128);
        uint4 v1 = *(const uint4*)(hsrc + (size_t)i1 * 128);
        uint4 v2 = *(const uint4*)(hsrc + (size_t)i2 * 128);
        uint4 v3 = *(const uint4*)(hsrc + (size_t)i3 * 128);
        a[0] += bf2f(v0.x & 0xffff) + bf2f(v1.x & 0xffff) + bf2f(v2.x & 0xffff) + bf2f(v3.x & 0xffff);
        a[1] += bf2f(v0.x >> 16)    + bf2f(v1.x >> 16)    + bf2f(v2.x >> 16)    + bf2f(v3.x >> 16);
        a[2] += bf2f(v0.y & 0xffff) + bf2f(v1.y & 0xffff) + bf2f(v2.y & 0xffff) + bf2f(v3.y & 0xffff);
        a[3] += bf2f(v0.y >> 16)    + bf2f(v1.y >> 16)    + bf2f(v2.y >> 16)    + bf2f(v3.y >> 16);
        a[4] += bf2f(v0.z & 0xffff) + bf2f(v1.z & 0xffff) + bf2f(v2.z & 0xffff) + bf2f(v3.z & 0xffff);
        a[5] += bf2f(v0.z >> 16)    + bf2f(v1.z >> 16)    + bf2f(v2.z >> 16)    + bf2f(v3.z >> 16);
        a[6] += bf2f(v0.w & 0xffff) + bf2f(v1.w & 0xffff) + bf2f(v2.w & 0xffff) + bf2f(v3.w & 0xffff);
        a[7] += bf2f(v0.w >> 16)    + bf2f(v1.w >> 16)    + bf2f(v2.w >> 16)    + bf2f(v3.w >> 16);
    }
    for (; k < e; ++k) {
        int i0 = cl[k];
        uint4 v0 = *(const uint4*)(hsrc + (size_t)i0 * 128);
        a[0] += bf2f(v0.x & 0xffff); a[1] += bf2f(v0.x >> 16);
        a[2] += bf2f(v0.y & 0xffff); a[3] += bf2f(v0.y >> 16);
        a[4] += bf2f(v0.z & 0xffff); a[5] += bf2f(v0.z >> 16);
        a[6] += bf2f(v0.w & 0xffff); a[7] += bf2f(v0.w >> 16);
    }
    float sc = (e > s) ? 1.0f / (float)(e - s) : 0.0f;
    uint4 o;
    o.x = f2bfbits(a[0] * sc) | ((unsigned)f2bfbits(a[1] * sc) << 16);
    o.y = f2bfbits(a[2] * sc) | ((unsigned)f2bfbits(a[3] * sc) << 16);
    o.z = f2bfbits(a[4] * sc) | ((unsigned)f2bfbits(a[5] * sc) << 16);
    o.w = f2bfbits(a[6] * sc) | ((unsigned)f2bfbits(a[7] * sc) << 16);
    *(uint4*)(agg + ((size_t)rel * NN + node) * 128 + lane * 8) = o;
}

// ---------------- layer GEMM (bf16 MFMA, streaming A) ----------------
// hout = relu(0.25*([agg0|agg1|agg2|agg3|hin] @ BT^T + bsum)) as bf16 [N,128].
// BM=64, BN=128, 10 K-chunks of 64 (source buffer = c>>1: agg0..3, then hin).
// 256 threads = 4 waves (2x2), wave tile 32x64 via 2x4 mfma_f32_16x16x32_bf16.
// LDS 24 KB (A 8K + B 16K) -> 6 blocks/CU. Chunk c+1 A/B preloaded into regs
// under chunk c's MFMA. XOR-swizzled LDS; LDS-staged contiguous epilogue.

__global__ __launch_bounds__(256, 6) void layer_gemm_kernel(
    const __hip_bfloat16* __restrict__ agg, const __hip_bfloat16* __restrict__ hin,
    __hip_bfloat16* __restrict__ hout, const __hip_bfloat16* __restrict__ BT,
    const float* __restrict__ bsum, int M) {
    __shared__ uint4 smem4[1536];    // 24 KB
    char* AsB = (char*)smem4;        // [64 rows][64 k] bf16, swizzled 16B chunks
    char* BsB = (char*)smem4 + 8192; // [128 n ][64 k]
    int t = threadIdx.x;
    int l = t & 63;
    int wave = t >> 6;
    int wm = wave >> 1, wn = wave & 1;
    int row0 = blockIdx.x * 64;

    int ar = t >> 2;                 // A stage: row 0..63
    int ap = t & 3;                  // A stage: 32B part
    int bn_ = t >> 1;                // B stage: n row 0..127
    int bj = t & 1;                  // B stage: which 32-elem half

    int lrow = l & 15;               // MFMA fragment row/col within 16
    int lkg = l >> 4;                // MFMA k-group 0..3

    bool arow_ok = (row0 + ar) < M;

    f32x4 acc[2][4];
#pragma unroll
    for (int i = 0; i < 2; ++i)
#pragma unroll
        for (int j = 0; j < 4; ++j) acc[i][j] = (f32x4){0.f, 0.f, 0.f, 0.f};

    uint4 areg[2], breg[4];
    // preload chunk 0
    {
        const __hip_bfloat16* asrc = agg;   // c=0 -> agg0, half 0
        if (arow_ok) {
            const __hip_bfloat16* ga = asrc + (size_t)(row0 + ar) * 128 + ap * 16;
            areg[0] = *(const uint4*)ga;
            areg[1] = *(const uint4*)(ga + 8);
        } else {
            areg[0] = make_uint4(0, 0, 0, 0);
            areg[1] = make_uint4(0, 0, 0, 0);
        }
        const __hip_bfloat16* gb = BT + (size_t)bn_ * KTOT + bj * 32;
#pragma unroll
        for (int j = 0; j < 4; ++j) breg[j] = *(const uint4*)(gb + j * 8);
    }

    for (int c = 0; c < 10; ++c) {
        if (c) __syncthreads();      // previous chunk's LDS reads done
        // ---- write staged regs -> LDS (swizzled) ----
        {
            int q0 = ap * 2, q1 = ap * 2 + 1;
            *(uint4*)(AsB + ar * 128 + ((q0 ^ (ar & 7)) << 4)) = areg[0];
            *(uint4*)(AsB + ar * 128 + ((q1 ^ (ar & 7)) << 4)) = areg[1];
#pragma unroll
            for (int j = 0; j < 4; ++j) {
                int q = bj * 4 + j;
                *(uint4*)(BsB + bn_ * 128 + ((q ^ (bn_ & 7)) << 4)) = breg[j];
            }
        }
        // ---- preload chunk c+1 into regs (latency hidden under MFMA) ----
        if (c + 1 < 10) {
            int cn = c + 1;
            int bsel = cn >> 1, half = cn & 1;
            const __hip_bfloat16* asrc =
                (bsel < 4) ? (agg + (size_t)bsel * NN * 128) : hin;
            if (arow_ok) {
                const __hip_bfloat16* ga =
                    asrc + (size_t)(row0 + ar) * 128 + half * 64 + ap * 16;
                areg[0] = *(const uint4*)ga;
                areg[1] = *(const uint4*)(ga + 8);
            }
            const __hip_bfloat16* gb = BT + (size_t)bn_ * KTOT + cn * 64 + bj * 32;
#pragma unroll
            for (int j = 0; j < 4; ++j) breg[j] = *(const uint4*)(gb + j * 8);
        }
        __syncthreads();
        // ---- MFMA over this K=64 chunk ----
#pragma unroll
        for (int kk = 0; kk < 2; ++kk) {
            s16x8 af[2], bfr[4];
            int q = kk * 4 + lkg;
#pragma unroll
            for (int mi = 0; mi < 2; ++mi) {
                int row = wm * 32 + mi * 16 + lrow;
                af[mi] = *(const s16x8*)(AsB + row * 128 + ((q ^ (row & 7)) << 4));
            }
#pragma unroll
            for (int ni = 0; ni < 4; ++ni) {
                int nrow = wn * 64 + ni * 16 + lrow;
                bfr[ni] = *(const s16x8*)(BsB + nrow * 128 + ((q ^ (nrow & 7)) << 4));
            }
#pragma unroll
            for (int mi = 0; mi < 2; ++mi)
#pragma unroll
                for (int ni = 0; ni < 4; ++ni)
                    acc[mi][ni] = __builtin_amdgcn_mfma_f32_16x16x32_bf16(
                        af[mi], bfr[ni], acc[mi][ni], 0, 0, 0);
        }
    }
    __syncthreads();   // LDS dead; reuse for C tile [64][128] bf16 (16 KB)

    // ---- epilogue: bias + relu*0.25 -> bf16 C tile in LDS (swizzled) ----
    {
        int cr = l >> 4;
        int cc = l & 15;
#pragma unroll
        for (int ni = 0; ni < 4; ++ni) {
            int colg = wn * 64 + ni * 16 + cc;
            float bv2 = bsum[colg];
            int q = colg >> 3;
            int cb = (colg & 7) * 2;
#pragma unroll
            for (int mi = 0; mi < 2; ++mi) {
#pragma unroll
                for (int r = 0; r < 4; ++r) {
                    int row = wm * 32 + mi * 16 + cr * 4 + r;
                    float v = fmaxf((acc[mi][ni][r] + bv2) * 0.25f, 0.f);
                    int byte = row * 256 + ((q ^ (row & 15)) << 4) + cb;
                    *(unsigned short*)((char*)smem4 + byte) = f2bfbits(v);
                }
            }
        }
    }
    __syncthreads();

    // ---- contiguous row writes: thread t owns row t>>2, quarter t&3 (64B) ----
    {
        int row = t >> 2;
        int part = t & 3;
        int grow = row0 + row;
        if (grow < M) {
            __hip_bfloat16* dst = hout + (size_t)grow * 128 + part * 32;
#pragma unroll
            for (int j = 0; j < 4; ++j) {
                int q = part * 4 + j;
                uint4 v = *(const uint4*)((char*)smem4 + row * 256 + ((q ^ (row & 15)) << 4));
                *(uint4*)(dst + j * 8) = v;
            }
        }
    }
}

// ---------------- final linear: out[M,16] = h[M,128] @ W[128,16] + b ----------------

__global__ void final_linear_kernel(const __hip_bfloat16* __restrict__ h,
                                    const float* __restrict__ W,
                                    const float* __restrict__ bias, float* __restrict__ out) {
    __shared__ float Ws[128 * 16];
    __shared__ float Hs[16 * 132];
    int tid = threadIdx.x;
    int node0 = blockIdx.x * 16;
    for (int i = tid; i < 2048; i += 256) Ws[i] = W[i];
    {
        int g = tid >> 4, c = tid & 15;
        int node = node0 + g;
        float f[8] = {};
        if (node < NN) {
            uint4 v = *(const uint4*)(h + (size_t)node * 128 + c * 8);
            f[0] = bf2f(v.x & 0xffff); f[1] = bf2f(v.x >> 16);
            f[2] = bf2f(v.y & 0xffff); f[3] = bf2f(v.y >> 16);
            f[4] = bf2f(v.z & 0xffff); f[5] = bf2f(v.z >> 16);
            f[6] = bf2f(v.w & 0xffff); f[7] = bf2f(v.w >> 16);
        }
#pragma unroll
        for (int j = 0; j < 8; ++j) Hs[g * 132 + c * 8 + j] = f[j];
    }
    __syncthreads();
    int g = tid >> 4;
    int c = tid & 15;
    int node = node0 + g;
    if (node >= NN) return;
    float acc = bias[c];
#pragma unroll 8
    for (int k = 0; k < 128; ++k) acc += Hs[g * 132 + k] * Ws[k * 16 + c];
    out[node * NCLS + c] = acc;
}

// ---------------- launch ----------------

extern "C" void kernel_launch(void* const* d_in, const int* in_sizes, int n_in,
                              void* d_out, int out_size, void* d_ws, size_t ws_size,
                              hipStream_t stream) {
    const float* x     = (const float*)d_in[0];
    const int*   e0    = (const int*)d_in[1];
    const int*   e1    = (const int*)d_in[2];
    const int*   e2    = (const int*)d_in[3];
    const int*   e3    = (const int*)d_in[4];
    const float* W_nbr = (const float*)d_in[5];
    const float* b_nbr = (const float*)d_in[6];
    const float* W_root= (const float*)d_in[7];
    const float* lin_w = (const float*)d_in[8];
    const float* lin_b = (const float*)d_in[9];
    float* out = (float*)d_out;

    // workspace bump allocator (256B aligned)
    char* p = (char*)d_ws;
    auto alloc = [&](size_t bytes) -> void* {
        void* q = (void*)p;
        p += (bytes + 255) & ~(size_t)255;
        return q;
    };
    int*   counts = (int*)alloc((size_t)RELS * NN * 4);
    int*   rowptr = (int*)alloc((size_t)RELS * (NN + 1) * 4);
    int*   col    = (int*)alloc((size_t)RELS * NE * 4);
    int*   bsums  = (int*)alloc((size_t)RELS * 128 * 4);
    float* bsum   = (float*)alloc((size_t)2 * 128 * 4);
    __hip_bfloat16* BT  = (__hip_bfloat16*)alloc((size_t)2 * 128 * KTOT * 2);
    __hip_bfloat16* agg = (__hip_bfloat16*)alloc((size_t)RELS * NN * 128 * 2);
    __hip_bfloat16* h0  = (__hip_bfloat16*)alloc((size_t)NN * 128 * 2);
    __hip_bfloat16* h1  = (__hip_bfloat16*)alloc((size_t)NN * 128 * 2);
    __hip_bfloat16* h2  = (__hip_bfloat16*)alloc((size_t)NN * 128 * 2);

    const int eblocks = (NE + 255) / 256;

    // CSR build (shared by both layers)
    hipMemsetAsync(counts, 0, (size_t)RELS * NN * 4, stream);
    hist_kernel<<<dim3(eblocks, RELS), 256, 0, stream>>>(e0, e1, e2, e3, counts);
    scanA_kernel<<<dim3(NCHUNK, RELS), SCAN_B, 0, stream>>>(counts, bsums);
    scanB_kernel<<<1, 64, 0, stream>>>(bsums, rowptr);
    scanC_kernel<<<dim3(NCHUNK, RELS), SCAN_B, 0, stream>>>(counts, bsums, rowptr);
    hipMemsetAsync(counts, 0, (size_t)RELS * NN * 4, stream);
    fill_kernel<<<dim3(eblocks, RELS), 256, 0, stream>>>(e0, e1, e2, e3, rowptr, counts, col);

    // weights -> bf16 transposed (+ root-sum fold + bias sum)
    wconv_kernel<<<(2 * 128 * KTOT + 256 + 255) / 256, 256, 0, stream>>>(
        W_nbr, W_root, b_nbr, BT, bsum);

    // x -> bf16 compact h0
    x2bf_kernel<<<(NN * 128 / 8 + 255) / 256, 256, 0, stream>>>(x, h0);

    const int gblocks = (NN + 63) / 64;

    // layer 1: h0 -> h1
    aggregate_kernel<<<dim3(NN / 16, RELS), 256, 0, stream>>>(rowptr, col, h0, agg);
    layer_gemm_kernel<<<gblocks, 256, 0, stream>>>(agg, h0, h1, BT, bsum, NN);
    // layer 2: h1 -> h2
    aggregate_kernel<<<dim3(NN / 16, RELS), 256, 0, stream>>>(rowptr, col, h1, agg);
    layer_gemm_kernel<<<gblocks, 256, 0, stream>>>(agg, h1, h2, BT + (size_t)128 * KTOT,
                                                   bsum + 128, NN);

    final_linear_kernel<<<(NN + 15) / 16, 256, 0, stream>>>(h2, lin_w, lin_b, out);
}